// Round 9
// baseline (85.872 us; speedup 1.0000x reference)
//
#include <hip/hip_runtime.h>
#include <hip/hip_bf16.h>
#include <cstdint>

// x: [8,8192,512] f32 -> LN over E=512 -> h=[16384,2048] bf16 (row-major flatten)
// W: [2048,512] f32, b: [512]; out = gelu(h @ W' + b'),
// W' = gamma-folded W (bf16, transposed), b' = b + beta @ W.
#define XROWS   65536
#define E       512
#define MROWS   16384
#define KDIM    2048
#define NDIM    512
#define NT      32        // K-steps of 64

typedef __attribute__((ext_vector_type(4))) float f32x4;
typedef __attribute__((ext_vector_type(8))) unsigned short u16x8;
typedef __attribute__((ext_vector_type(8))) __bf16 bf16x8;

__device__ __forceinline__ unsigned short f2bf(float f) {
  unsigned u = __builtin_bit_cast(unsigned, f);
  u += 0x7FFFu + ((u >> 16) & 1u);   // round-to-nearest-even
  return (unsigned short)(u >> 16);
}

typedef const __attribute__((address_space(1))) unsigned char ga_u8;
typedef __attribute__((address_space(3))) unsigned char ls_u8;
__device__ __forceinline__ void gload16(const void* g, void* l) {
  __builtin_amdgcn_global_load_lds((ga_u8*)g, (ls_u8*)l, 16, 0, 0);
}

// fast gelu (tanh form), |err vs erf form| <= ~3e-3 << 0.094 threshold
__device__ __forceinline__ float gelu_f(float v) {
  float p = v * (2.3022083f + 0.1029432f * (v * v));
  p = fminf(p, 80.0f);
  const float Ee = exp2f(p);
  return v * Ee * __builtin_amdgcn_rcpf(Ee + 1.0f);
}

// ---------------------------------------------------------------------------
// W [2048][512] f32 -> WT [512][2048] bf16, gamma folded in:
//   WT[n][k] = bf16(gamma[k % 512] * W[k][n])
// ---------------------------------------------------------------------------
__global__ __launch_bounds__(256) void wt_kernel(const float* __restrict__ W,
                                                 const float* __restrict__ gamma,
                                                 unsigned short* __restrict__ WT) {
  __shared__ float tile[64][68];
  const int t  = threadIdx.x;
  const int bk = blockIdx.x >> 3;
  const int bn = blockIdx.x & 7;
  const int c4 = (t & 15) * 4;
#pragma unroll
  for (int i = 0; i < 4; ++i) {
    const int r = (t >> 4) + i * 16;
    const f32x4 v = *(const f32x4*)&W[(size_t)(bk * 64 + r) * NDIM + bn * 64 + c4];
    tile[r][c4 + 0] = v.x; tile[r][c4 + 1] = v.y;
    tile[r][c4 + 2] = v.z; tile[r][c4 + 3] = v.w;
  }
  __syncthreads();
#pragma unroll
  for (int j = 0; j < 2; ++j) {
    const int n  = j * 32 + (t >> 3);
    const int kb = (t & 7) * 8;
    const int kg0 = (bk & 7) * 64 + kb;
    const f32x4 g0 = *(const f32x4*)(gamma + kg0);
    const f32x4 g1 = *(const f32x4*)(gamma + kg0 + 4);
    const float gg[8] = {g0.x, g0.y, g0.z, g0.w, g1.x, g1.y, g1.z, g1.w};
    u16x8 o;
#pragma unroll
    for (int q = 0; q < 8; ++q) o[q] = f2bf(gg[q] * tile[kb + q][n]);
    *(u16x8*)&WT[(size_t)(bn * 64 + n) * KDIM + bk * 64 + kb] = o;
  }
}

// ---------------------------------------------------------------------------
// beta fold: partial[32][512] then reduce + b.
// ---------------------------------------------------------------------------
__global__ __launch_bounds__(256) void kbias1(const float* __restrict__ W,
                                              const float* __restrict__ beta,
                                              float* __restrict__ partial) {
  const int bk = blockIdx.x, tid = threadIdx.x;
  float a0 = 0.f, a1 = 0.f;
  for (int k = 0; k < 64; ++k) {
    const int kg = bk * 64 + k;
    const float be = beta[kg & (E - 1)];
    a0 += be * W[(size_t)kg * NDIM + tid];
    a1 += be * W[(size_t)kg * NDIM + 256 + tid];
  }
  partial[bk * NDIM + tid] = a0;
  partial[bk * NDIM + 256 + tid] = a1;
}

__global__ __launch_bounds__(256) void kbias2(const float* __restrict__ b,
                                              const float* __restrict__ partial,
                                              float* __restrict__ biasf) {
  const int c = blockIdx.x * 256 + threadIdx.x;
  float s = b[c];
  for (int j = 0; j < 32; ++j) s += partial[j * NDIM + c];
  biasf[c] = s;
}

// ---------------------------------------------------------------------------
// LayerNorm: one wave per x-row of 512 f32 -> bf16 h (gamma/beta folded out).
// ---------------------------------------------------------------------------
__global__ __launch_bounds__(256, 4) void ln_kernel(const float* __restrict__ x,
                                                    unsigned short* __restrict__ h) {
  const int w = threadIdx.x >> 6, l = threadIdx.x & 63;
  const size_t row = (size_t)blockIdx.x * 4 + w;
  const float* xr = x + row * E + l * 8;
  const f32x4 v0 = *(const f32x4*)xr;
  const f32x4 v1 = *(const f32x4*)(xr + 4);
  float xv[8] = {v0.x, v0.y, v0.z, v0.w, v1.x, v1.y, v1.z, v1.w};
  float s = 0.f, q = 0.f;
#pragma unroll
  for (int j = 0; j < 8; ++j) { s += xv[j]; q += xv[j] * xv[j]; }
#pragma unroll
  for (int off = 32; off > 0; off >>= 1) {
    s += __shfl_xor(s, off);
    q += __shfl_xor(q, off);
  }
  const float mean = s * (1.0f / E);
  const float var  = q * (1.0f / E) - mean * mean;
  const float rstd = rsqrtf(var + 1e-6f);
  const float nm   = -mean * rstd;
  u16x8 o;
#pragma unroll
  for (int j = 0; j < 8; ++j) o[j] = f2bf(xv[j] * rstd + nm);
  *(u16x8*)(h + row * E + l * 8) = o;
}

// ---------------------------------------------------------------------------
// GEMM, 8-phase-template port (m201-class) at BM=256 x BN=128, BK=64.
// 512 threads = 8 waves (2M x 4N); wave output 128x32 -> acc[8][2] f32x4.
// LDS 96KB: A[pp][half] 2x2x16KB @0, B[pp] 2x16KB @65536 (T2 pre-swizzled
// via gload_lds linear-dest + swizzled global source, proven R7 math).
// Per tile tau: 4 phases (mh,kk): {6 ds_read_b128; 2 gload stage; s_barrier;
// lgkmcnt(0)+sched_barrier(0); setprio(1); 8 MFMA; setprio(0); s_barrier}.
// Counted-wait audit (vmcnt counts VMEM only; each wave issues identically):
//   ph0 stages B(tau+1)x2 ; ph1 A(tau+1,mh1)x2 ; ph2 A(tau+2,mh0)x2 ;
//   ph3 end: vmcnt(2)  -> drains tile tau+1's 6 loads, leaves A(tau+2,mh0).
//   Prologue: tile0 (6) + A(1,mh0) (2); vmcnt(2); barrier  -> steady at tau=0.
//   Tail: tau==30 -> vmcnt(0) (ph2 stage skipped); tau==31 -> no wait.
// Slot safety: A(t,mh0) read only in ph0/ph1 (freed at ph1 end: lgkmcnt(0)
// pre-final-barrier) -> restage at ph2; B/A-mh1 freed at ph3 end.
// ---------------------------------------------------------------------------
#define VMCNT(n) asm volatile("s_waitcnt vmcnt(" #n ")" ::: "memory")
#define LGKM0()  asm volatile("s_waitcnt lgkmcnt(0)" ::: "memory")

__global__ __launch_bounds__(512, 1) void gemm_kernel(const unsigned short* __restrict__ A,
                                                      const unsigned short* __restrict__ Bt,
                                                      const float* __restrict__ biasf,
                                                      float* __restrict__ out) {
  __shared__ char smem[98304];   // A: [pp]*32768 + [half]*16384; B: 65536 + [pp]*16384
  const int tid = threadIdx.x;
  const int l = tid & 63, w = tid >> 6;
  const int l7 = l & 7, l15 = l & 15, lhi = l >> 4;
  const int wr = w >> 2, wc = w & 3;

  // XCD chunking: grid 256 = 8 XCDs x 32; bn in low 2 bits of wg
  const int wg = ((blockIdx.x & 7) << 5) | (blockIdx.x >> 3);
  const int bn = wg & 3;
  const int bm = wg >> 2;
  const size_t arow0 = (size_t)bm * 256;
  const int    ncol0 = bn * 128;

  // staging: one call = 64 rows x 128B = 512 lanes x 16B; source pre-swizzled
  const int srow = tid >> 3;                       // 0..63
  const int swz  = ((tid & 7) * 16) ^ ((srow & 7) << 4);
  const char* gA = (const char*)A  + ((size_t)(arow0 + srow) * KDIM) * 2 + swz;
  const char* gB = (const char*)Bt + ((size_t)(ncol0 + srow) * KDIM) * 2 + swz;

  auto stageA = [&](int t, int h, int mh) {   // one A-quarter (1 VMEM op/lane)
    gload16(gA + ((size_t)(h * 128 + mh * 64) * KDIM) * 2 + (size_t)t * 128,
            smem + (t & 1) * 32768 + h * 16384 + (mh * 64 + w * 8) * 128);
  };
  auto stageB = [&](int t, int c) {            // one B 64-row chunk
    gload16(gB + ((size_t)(c * 64) * KDIM) * 2 + (size_t)t * 128,
            smem + 65536 + (t & 1) * 16384 + (c * 64 + w * 8) * 128);
  };

  f32x4 acc[8][2];
#pragma unroll
  for (int m = 0; m < 8; ++m) {
    acc[m][0] = (f32x4){0.f, 0.f, 0.f, 0.f};
    acc[m][1] = (f32x4){0.f, 0.f, 0.f, 0.f};
  }

  const int cs0 = (lhi * 16) ^ (l7 * 16);

  // ds_read + MFMA cluster for phase (mh, kk) of tile with parity p
#define DS_LOADS(p, mh, kk)                                                     \
  const char* Ab = smem + (p) * 32768 + wr * 16384;                             \
  const char* Bb = smem + 65536 + (p) * 16384;                                  \
  const int co = cs0 ^ ((kk) * 64);                                             \
  bf16x8 a0 = *(const bf16x8*)(Ab + ((mh) * 64 +  0 + l15) * 128 + co);         \
  bf16x8 a1 = *(const bf16x8*)(Ab + ((mh) * 64 + 16 + l15) * 128 + co);         \
  bf16x8 a2 = *(const bf16x8*)(Ab + ((mh) * 64 + 32 + l15) * 128 + co);         \
  bf16x8 a3 = *(const bf16x8*)(Ab + ((mh) * 64 + 48 + l15) * 128 + co);         \
  bf16x8 b0 = *(const bf16x8*)(Bb + (wc * 32 +  0 + l15) * 128 + co);           \
  bf16x8 b1 = *(const bf16x8*)(Bb + (wc * 32 + 16 + l15) * 128 + co)

#define MFMA8(mh)                                                               \
  acc[(mh)*4+0][0] = __builtin_amdgcn_mfma_f32_16x16x32_bf16(a0, b0, acc[(mh)*4+0][0], 0,0,0); \
  acc[(mh)*4+0][1] = __builtin_amdgcn_mfma_f32_16x16x32_bf16(a0, b1, acc[(mh)*4+0][1], 0,0,0); \
  acc[(mh)*4+1][0] = __builtin_amdgcn_mfma_f32_16x16x32_bf16(a1, b0, acc[(mh)*4+1][0], 0,0,0); \
  acc[(mh)*4+1][1] = __builtin_amdgcn_mfma_f32_16x16x32_bf16(a1, b1, acc[(mh)*4+1][1], 0,0,0); \
  acc[(mh)*4+2][0] = __builtin_amdgcn_mfma_f32_16x16x32_bf16(a2, b0, acc[(mh)*4+2][0], 0,0,0); \
  acc[(mh)*4+2][1] = __builtin_amdgcn_mfma_f32_16x16x32_bf16(a2, b1, acc[(mh)*4+2][1], 0,0,0); \
  acc[(mh)*4+3][0] = __builtin_amdgcn_mfma_f32_16x16x32_bf16(a3, b0, acc[(mh)*4+3][0], 0,0,0); \
  acc[(mh)*4+3][1] = __builtin_amdgcn_mfma_f32_16x16x32_bf16(a3, b1, acc[(mh)*4+3][1], 0,0,0)

  // prologue: tile0 fully + A(1, mh0); counted wait leaves the 2 newest
  stageA(0, 0, 0); stageA(0, 1, 0);
  stageA(0, 0, 1); stageA(0, 1, 1);
  stageB(0, 0);    stageB(0, 1);
  stageA(1, 0, 0); stageA(1, 1, 0);
  VMCNT(2);
  __builtin_amdgcn_s_barrier();

  for (int tau = 0; tau < NT; ++tau) {
    const int p = tau & 1;
    { // phase 0: (mh0, kk0) | stage B(tau+1)
      DS_LOADS(p, 0, 0);
      if (tau + 1 < NT) { stageB(tau + 1, 0); stageB(tau + 1, 1); }
      __builtin_amdgcn_s_barrier();
      LGKM0(); __builtin_amdgcn_sched_barrier(0);
      __builtin_amdgcn_s_setprio(1); MFMA8(0); __builtin_amdgcn_s_setprio(0);
      __builtin_amdgcn_s_barrier();
    }
    { // phase 1: (mh0, kk1) | stage A(tau+1, mh1)  [A(tau,mh0) freed after this]
      DS_LOADS(p, 0, 1);
      if (tau + 1 < NT) { stageA(tau + 1, 0, 1); stageA(tau + 1, 1, 1); }
      __builtin_amdgcn_s_barrier();
      LGKM0(); __builtin_amdgcn_sched_barrier(0);
      __builtin_amdgcn_s_setprio(1); MFMA8(0); __builtin_amdgcn_s_setprio(0);
      __builtin_amdgcn_s_barrier();
    }
    { // phase 2: (mh1, kk0) | stage A(tau+2, mh0) into slots freed at ph1 end
      DS_LOADS(p, 1, 0);
      if (tau + 2 < NT) { stageA(tau + 2, 0, 0); stageA(tau + 2, 1, 0); }
      __builtin_amdgcn_s_barrier();
      LGKM0(); __builtin_amdgcn_sched_barrier(0);
      __builtin_amdgcn_s_setprio(1); MFMA8(1); __builtin_amdgcn_s_setprio(0);
      __builtin_amdgcn_s_barrier();
    }
    { // phase 3: (mh1, kk1) | counted wait for tile tau+1, then release bufs
      DS_LOADS(p, 1, 1);
      __builtin_amdgcn_s_barrier();
      LGKM0(); __builtin_amdgcn_sched_barrier(0);
      __builtin_amdgcn_s_setprio(1); MFMA8(1); __builtin_amdgcn_s_setprio(0);
      if (tau + 2 < NT)      VMCNT(2);   // tile tau+1 landed; A(tau+2,mh0) in flight
      else if (tau + 1 < NT) VMCNT(0);   // tail: tau==30
      __builtin_amdgcn_s_barrier();
    }
  }
#undef DS_LOADS
#undef MFMA8

  // epilogue: bias + fast gelu. C/D layout (m89): col = l&15, row = (l>>4)*4+reg
#pragma unroll
  for (int n = 0; n < 2; ++n) {
    const int col = ncol0 + wc * 32 + n * 16 + l15;
    const float bb = biasf[col];
#pragma unroll
    for (int m = 0; m < 8; ++m) {
      const size_t rbase = arow0 + wr * 128 + m * 16 + lhi * 4;
#pragma unroll
      for (int r = 0; r < 4; ++r) {
        const float v = acc[m][n][r] + bb;
        out[(rbase + r) * NDIM + col] = gelu_f(v);
      }
    }
  }
}

// ---------------------------------------------------------------------------
extern "C" void kernel_launch(void* const* d_in, const int* in_sizes, int n_in,
                              void* d_out, int out_size, void* d_ws, size_t ws_size,
                              hipStream_t stream) {
  const float* x     = (const float*)d_in[0];
  const float* gamma = (const float*)d_in[1];
  const float* beta  = (const float*)d_in[2];
  const float* W     = (const float*)d_in[3];
  const float* b     = (const float*)d_in[4];
  float* out = (float*)d_out;

  // ws layout: WT 2MB | h 64MB | partial 64KB | biasf 2KB
  char* p = (char*)d_ws;
  unsigned short* WT = (unsigned short*)p;            p += (size_t)NDIM * KDIM * 2;
  unsigned short* h  = (unsigned short*)p;            p += (size_t)MROWS * KDIM * 2;
  float* partial     = (float*)p;                     p += (size_t)32 * NDIM * 4;
  float* biasf       = (float*)p;

  wt_kernel<<<256, 256, 0, stream>>>(W, gamma, WT);
  kbias1<<<32, 256, 0, stream>>>(W, beta, partial);
  kbias2<<<2, 256, 0, stream>>>(b, partial, biasf);
  ln_kernel<<<XROWS / 4, 256, 0, stream>>>(x, h);
  gemm_kernel<<<(MROWS / 256) * 4, 512, 0, stream>>>(h, WT, biasf, out);
}

// Round 10
// 79.988 us; speedup vs baseline: 1.0736x; 1.0736x over previous
//
#include <hip/hip_runtime.h>
#include <hip/hip_bf16.h>
#include <cstdint>

// x: [8,8192,512] f32 -> LN over E=512 -> h=[16384,2048] bf16 (row-major flatten)
// W: [2048,512] f32, b: [512]; out = gelu(h @ W' + b'),
// W' = gamma-folded W (bf16, transposed), b' = b + beta @ W.
#define XROWS   65536
#define E       512
#define MROWS   16384
#define KDIM    2048
#define NDIM    512
#define NT      32        // K-steps of 64

typedef __attribute__((ext_vector_type(4))) float f32x4;
typedef __attribute__((ext_vector_type(8))) unsigned short u16x8;
typedef __attribute__((ext_vector_type(8))) __bf16 bf16x8;

__device__ __forceinline__ unsigned short f2bf(float f) {
  unsigned u = __builtin_bit_cast(unsigned, f);
  u += 0x7FFFu + ((u >> 16) & 1u);   // round-to-nearest-even
  return (unsigned short)(u >> 16);
}

typedef const __attribute__((address_space(1))) unsigned char ga_u8;
typedef __attribute__((address_space(3))) unsigned char ls_u8;
__device__ __forceinline__ void gload16(const void* g, void* l) {
  __builtin_amdgcn_global_load_lds((ga_u8*)g, (ls_u8*)l, 16, 0, 0);
}

// fast gelu (tanh form), |err vs erf form| <= ~3e-3 << 0.094 threshold
__device__ __forceinline__ float gelu_f(float v) {
  float p = v * (2.3022083f + 0.1029432f * (v * v));
  p = fminf(p, 80.0f);
  const float Ee = exp2f(p);
  return v * Ee * __builtin_amdgcn_rcpf(Ee + 1.0f);
}

// ---------------------------------------------------------------------------
// Merged setup: blocks 0..255 -> WT transpose+gamma-fold; 256..287 -> beta
// partials. (Independent work, both stream W; one launch instead of two.)
//   WT[n][k] = bf16(gamma[k % 512] * W[k][n])
//   partial[bk][c] = sum_{k in bk*64..} beta[k%512] * W[k][c]
// ---------------------------------------------------------------------------
__global__ __launch_bounds__(256) void setup_kernel(const float* __restrict__ W,
                                                    const float* __restrict__ gamma,
                                                    const float* __restrict__ beta,
                                                    unsigned short* __restrict__ WT,
                                                    float* __restrict__ partial) {
  __shared__ float tile[64][68];
  const int t = threadIdx.x;
  if (blockIdx.x >= 256) {           // beta-fold partials
    const int bk = blockIdx.x - 256;
    float a0 = 0.f, a1 = 0.f;
    for (int k = 0; k < 64; ++k) {
      const int kg = bk * 64 + k;
      const float be = beta[kg & (E - 1)];
      a0 += be * W[(size_t)kg * NDIM + t];
      a1 += be * W[(size_t)kg * NDIM + 256 + t];
    }
    partial[bk * NDIM + t] = a0;
    partial[bk * NDIM + 256 + t] = a1;
    return;
  }
  const int bk = blockIdx.x >> 3;
  const int bn = blockIdx.x & 7;
  const int c4 = (t & 15) * 4;
#pragma unroll
  for (int i = 0; i < 4; ++i) {
    const int r = (t >> 4) + i * 16;
    const f32x4 v = *(const f32x4*)&W[(size_t)(bk * 64 + r) * NDIM + bn * 64 + c4];
    tile[r][c4 + 0] = v.x; tile[r][c4 + 1] = v.y;
    tile[r][c4 + 2] = v.z; tile[r][c4 + 3] = v.w;
  }
  __syncthreads();
#pragma unroll
  for (int j = 0; j < 2; ++j) {
    const int n  = j * 32 + (t >> 3);
    const int kb = (t & 7) * 8;
    const int kg0 = (bk & 7) * 64 + kb;
    const f32x4 g0 = *(const f32x4*)(gamma + kg0);
    const f32x4 g1 = *(const f32x4*)(gamma + kg0 + 4);
    const float gg[8] = {g0.x, g0.y, g0.z, g0.w, g1.x, g1.y, g1.z, g1.w};
    u16x8 o;
#pragma unroll
    for (int q = 0; q < 8; ++q) o[q] = f2bf(gg[q] * tile[kb + q][n]);
    *(u16x8*)&WT[(size_t)(bn * 64 + n) * KDIM + bk * 64 + kb] = o;
  }
}

__global__ __launch_bounds__(256) void kbias2(const float* __restrict__ b,
                                              const float* __restrict__ partial,
                                              float* __restrict__ biasf) {
  const int c = blockIdx.x * 256 + threadIdx.x;
  float s = b[c];
  for (int j = 0; j < 32; ++j) s += partial[j * NDIM + c];
  biasf[c] = s;
}

// ---------------------------------------------------------------------------
// LayerNorm: one wave per TWO x-rows of 512 f32 -> bf16 h.
// Two rows/wave gives the serial shfl reduction chains ILP (4 independent
// values through the 6-round tree) and widens the load phase -> halves the
// exposed latency per row if ln is latency-bound (probe). Per-row summation
// order identical to the 1-row version -> bit-identical h.
// ---------------------------------------------------------------------------
__global__ __launch_bounds__(256, 4) void ln_kernel(const float* __restrict__ x,
                                                    unsigned short* __restrict__ h) {
  const int w = threadIdx.x >> 6, l = threadIdx.x & 63;
  const size_t row = (size_t)blockIdx.x * 8 + w * 2;   // rows row, row+1
  const float* xr = x + row * E + l * 8;
  const f32x4 a0 = *(const f32x4*)xr;
  const f32x4 a1 = *(const f32x4*)(xr + 4);
  const f32x4 b0 = *(const f32x4*)(xr + E);
  const f32x4 b1 = *(const f32x4*)(xr + E + 4);
  float av[8] = {a0.x, a0.y, a0.z, a0.w, a1.x, a1.y, a1.z, a1.w};
  float bv[8] = {b0.x, b0.y, b0.z, b0.w, b1.x, b1.y, b1.z, b1.w};
  float s0 = 0.f, q0 = 0.f, s1 = 0.f, q1 = 0.f;
#pragma unroll
  for (int j = 0; j < 8; ++j) {
    s0 += av[j]; q0 += av[j] * av[j];
    s1 += bv[j]; q1 += bv[j] * bv[j];
  }
#pragma unroll
  for (int off = 32; off > 0; off >>= 1) {
    s0 += __shfl_xor(s0, off); q0 += __shfl_xor(q0, off);
    s1 += __shfl_xor(s1, off); q1 += __shfl_xor(q1, off);
  }
  const float mean0 = s0 * (1.0f / E);
  const float rstd0 = rsqrtf(q0 * (1.0f / E) - mean0 * mean0 + 1e-6f);
  const float nm0   = -mean0 * rstd0;
  const float mean1 = s1 * (1.0f / E);
  const float rstd1 = rsqrtf(q1 * (1.0f / E) - mean1 * mean1 + 1e-6f);
  const float nm1   = -mean1 * rstd1;
  u16x8 o0, o1;
#pragma unroll
  for (int j = 0; j < 8; ++j) {
    o0[j] = f2bf(av[j] * rstd0 + nm0);
    o1[j] = f2bf(bv[j] * rstd1 + nm1);
  }
  *(u16x8*)(h + row * E + l * 8) = o0;
  *(u16x8*)(h + (row + 1) * E + l * 8) = o1;
}

// ---------------------------------------------------------------------------
// GEMM (UNCHANGED champion, 83.7 µs config): h x WT -> out f32, + bias+gelu.
// m97-faithful: 128x128 tile, BK=64, SINGLE 32KB buffer, 2 barriers/K-step,
// gload_lds staging (linear dest + pre-swizzled source; T2 XOR on ds_read),
// __launch_bounds__(256,3). T1 XCD-chunked bijective swizzle (512 = 8x64).
// ---------------------------------------------------------------------------
__global__ __launch_bounds__(256, 3) void gemm_kernel(const unsigned short* __restrict__ A,
                                                      const unsigned short* __restrict__ Bt,
                                                      const float* __restrict__ biasf,
                                                      float* __restrict__ out) {
  __shared__ char smem[32768];   // A 16KB @0, B 16KB @16384
  const int tid = threadIdx.x;
  const int l = tid & 63, w = tid >> 6;
  const int l7 = l & 7, l15 = l & 15, lhi = l >> 4;
  const int wr = w >> 1, wc = w & 1;

  // XCD chunking: grid 512 = 8 XCDs x 64; bn in low 2 bits of wg
  const int wg = ((blockIdx.x & 7) << 6) | (blockIdx.x >> 3);
  const int bn = wg & 3;
  const int bm = wg >> 2;
  const size_t arow0 = (size_t)bm * 128;
  const int    brow0 = bn * 128;

  // staging: thread covers rows {i*32 + w*8 + (l>>3)}, swizzled source col
  const int srow = w * 8 + (l >> 3);
  const int swz  = (l7 * 16) ^ ((l >> 3) << 4);
  const char* gA = (const char*)A  + ((size_t)(arow0 + srow) * KDIM) * 2 + swz;
  const char* gB = (const char*)Bt + ((size_t)(brow0 + srow) * KDIM) * 2 + swz;

  f32x4 acc[4][4];
#pragma unroll
  for (int m = 0; m < 4; ++m)
#pragma unroll
    for (int n = 0; n < 4; ++n) acc[m][n] = (f32x4){0.f, 0.f, 0.f, 0.f};

  // frag-read swizzled k-byte for kk=0; kk=1 flips bit 6 (outside swizzle)
  const int cs0 = (lhi * 16) ^ (l7 * 16);

  for (int t = 0; t < NT; ++t) {
    __syncthreads();               // all waves done reading buffer
    {
      const char* pa = gA + (size_t)t * 128;
      const char* pb = gB + (size_t)t * 128;
#pragma unroll
      for (int i = 0; i < 4; ++i) {
        gload16(pa + (size_t)i * 32 * KDIM * 2, smem + (i * 32 + w * 8) * 128);
        gload16(pb + (size_t)i * 32 * KDIM * 2, smem + 16384 + (i * 32 + w * 8) * 128);
      }
    }
    __syncthreads();               // drains vmcnt(0): staged data visible
#pragma unroll
    for (int kk = 0; kk < 2; ++kk) {
      const int co = cs0 ^ (kk * 64);
      bf16x8 av[4], bv[4];
#pragma unroll
      for (int m = 0; m < 4; ++m)
        av[m] = *(const bf16x8*)(smem + (wr * 64 + m * 16 + l15) * 128 + co);
#pragma unroll
      for (int n = 0; n < 4; ++n)
        bv[n] = *(const bf16x8*)(smem + 16384 + (wc * 64 + n * 16 + l15) * 128 + co);
#pragma unroll
      for (int m = 0; m < 4; ++m)
#pragma unroll
        for (int n = 0; n < 4; ++n)
          acc[m][n] = __builtin_amdgcn_mfma_f32_16x16x32_bf16(av[m], bv[n],
                                                              acc[m][n], 0, 0, 0);
    }
  }

  // epilogue: bias + fast gelu. C/D layout (m89): col = l&15, row = (l>>4)*4+reg
#pragma unroll
  for (int n = 0; n < 4; ++n) {
    const int col = brow0 + wc * 64 + n * 16 + l15;
    const float bb = biasf[col];
#pragma unroll
    for (int m = 0; m < 4; ++m) {
      const size_t rbase = arow0 + wr * 64 + m * 16 + lhi * 4;
#pragma unroll
      for (int r = 0; r < 4; ++r) {
        const float v = acc[m][n][r] + bb;
        out[(rbase + r) * NDIM + col] = gelu_f(v);
      }
    }
  }
}

// ---------------------------------------------------------------------------
extern "C" void kernel_launch(void* const* d_in, const int* in_sizes, int n_in,
                              void* d_out, int out_size, void* d_ws, size_t ws_size,
                              hipStream_t stream) {
  const float* x     = (const float*)d_in[0];
  const float* gamma = (const float*)d_in[1];
  const float* beta  = (const float*)d_in[2];
  const float* W     = (const float*)d_in[3];
  const float* b     = (const float*)d_in[4];
  float* out = (float*)d_out;

  // ws layout: WT 2MB | h 64MB | partial 64KB | biasf 2KB
  char* p = (char*)d_ws;
  unsigned short* WT = (unsigned short*)p;            p += (size_t)NDIM * KDIM * 2;
  unsigned short* h  = (unsigned short*)p;            p += (size_t)MROWS * KDIM * 2;
  float* partial     = (float*)p;                     p += (size_t)32 * NDIM * 4;
  float* biasf       = (float*)p;

  setup_kernel<<<288, 256, 0, stream>>>(W, gamma, beta, WT, partial);
  kbias2<<<2, 256, 0, stream>>>(b, partial, biasf);
  ln_kernel<<<XROWS / 8, 256, 0, stream>>>(x, h);
  gemm_kernel<<<(MROWS / 128) * 4, 256, 0, stream>>>(h, WT, biasf, out);
}